// Round 12
// baseline (1272.654 us; speedup 1.0000x reference)
//
#include <hip/hip_runtime.h>
#include <hip/hip_bf16.h>

typedef __attribute__((ext_vector_type(4))) float f32x4;
typedef __attribute__((ext_vector_type(8))) short bf16x8;
typedef unsigned int   u32;
typedef unsigned short u16;

#define DPAD 8
#define B_   8
#define C_   512
#define T_   8192
#define S_   256

// workspace byte offsets
#define OFF_WBIG 0u          // u16[1024*1024]      = 2,097,152 B
#define OFF_W2   2097152u    // u16[768*512]        =   786,432 B
#define OFF_B1   2883584u    // float[1024]
#define OFF_B2   2887680u    // float[768]
#define OFF_XT   2891776u    // u16[8*(8192+8)*512] = 67,174,400 B
#define OFF_ZT   70066176u   // u16[8*8192*512]     = 67,108,864 B

__device__ __forceinline__ u16 f2bf(float f) {
  u32 u = __builtin_bit_cast(u32, f);
  u += 0x7FFFu + ((u >> 16) & 1u);
  return (u16)(u >> 16);
}
__device__ __forceinline__ float sigm_(float x) { return 1.0f / (1.0f + __expf(-x)); }
__device__ __forceinline__ float tanh_(float x) { return 2.0f / (1.0f + __expf(-2.0f * x)) - 1.0f; }

__device__ __forceinline__ void gload_lds16(const void* g, void* l) {
  __builtin_amdgcn_global_load_lds(
      (const __attribute__((address_space(1))) void*)g,
      (__attribute__((address_space(3))) void*)l, 16, 0, 0);
}

// ---------------- pack weights / biases, zero Xt pad rows ----------------
__global__ void pack_kernel(const float* __restrict__ fw, const float* __restrict__ fb,
                            const float* __restrict__ gw, const float* __restrict__ gb,
                            const float* __restrict__ rw, const float* __restrict__ rb,
                            const float* __restrict__ sw, const float* __restrict__ sb,
                            u16* __restrict__ Wbig, u16* __restrict__ W2,
                            float* __restrict__ b1, float* __restrict__ b2,
                            u16* __restrict__ Xt)
{
  int idx = blockIdx.x * 256 + threadIdx.x;
  if (idx < 1048576) {                    // Wbig[row][k], row 2i=filter i, 2i+1=gate i
    int row = idx >> 10, k = idx & 1023;  // k<512: tap1 (x[t]); k>=512: tap0 (x[t-d])
    int i = row >> 1;
    const float* src = (row & 1) ? gw : fw;
    float v = src[((i << 9) + (k & 511)) * 2 + ((k < 512) ? 1 : 0)];
    Wbig[idx] = f2bf(v);
    return;
  }
  idx -= 1048576;
  if (idx < 393216) {                     // W2[r][k]: r<512 res, else skip
    int r = idx >> 9, k = idx & 511;
    float v = (r < 512) ? rw[(r << 9) + k] : sw[((r - 512) << 9) + k];
    W2[idx] = f2bf(v);
    return;
  }
  idx -= 393216;
  if (idx < 1024) { b1[idx] = (idx & 1) ? gb[idx >> 1] : fb[idx >> 1]; return; }
  idx -= 1024;
  if (idx < 768) { b2[idx] = (idx < 512) ? rb[idx] : sb[idx - 512]; return; }
  idx -= 768;
  if (idx < B_ * DPAD * C_) {             // zero causal pad rows of Xt
    int b = idx >> 12;                    // DPAD*C_ = 4096
    int rest = idx & 4095;
    Xt[(size_t)b * (T_ + DPAD) * C_ + rest] = 0;
  }
}

// ---------------- x [B][C][T] f32 -> Xt [B][DPAD+T][C] bf16 ----------------
__global__ __launch_bounds__(256) void transpose_kernel(const float* __restrict__ x,
                                                        u16* __restrict__ Xt)
{
  __shared__ float tile[64][65];
  int bid = blockIdx.x;
  int ct = bid & 7, tt = (bid >> 3) & 127, b = bid >> 10;
  int w = threadIdx.x >> 6, ln = threadIdx.x & 63;
  const float* xp = x + ((size_t)(b * C_ + ct * 64)) * T_ + tt * 64;
#pragma unroll
  for (int r = 0; r < 16; ++r) {
    int cl = r * 4 + w;
    tile[cl][ln] = xp[(size_t)cl * T_ + ln];
  }
  __syncthreads();
  u16* op = Xt + ((size_t)b * (T_ + DPAD) + DPAD + tt * 64) * C_ + ct * 64;
#pragma unroll
  for (int r = 0; r < 16; ++r) {
    int tl = r * 4 + w;
    op[(size_t)tl * C_ + ln] = f2bf(tile[ln][tl]);
  }
}

// ---------------- GEMM1: 128x128 tile, BK=32, 4 waves, 32KB LDS dbuf ---------------
// Occupancy play: 4 blocks/CU (16 waves) so barrier/drain bubbles of one block
// hide under other blocks' MFMA. Round-10 1-barrier pipeline per K-tile:
// {ds_read 8 frags; stage 4 gloads of tile t+1; lgkm(0); setprio; 16 MFMA;
//  setprio; vmcnt(0); s_barrier}. BK=32 frag reads are 16 consecutive 64B rows
// = contiguous 1KB per wave-read -> conflict-free without swizzle.
// Tap select is per-tile uniform: tiles 0..15 read gB1 (k<512, x[t]),
// tiles 16..31 read gB2 = gB1 - d*C - 512 (k>=512, x[t-d]; pad rows zero).
__global__ __launch_bounds__(256, 4) void gemm1_kernel(
    const u16* __restrict__ W, const u16* __restrict__ Xt,
    const float* __restrict__ b1, u16* __restrict__ Zt,
    const int* __restrict__ dptr)
{
  __shared__ __align__(16) u16 smem[16384];   // 32 KB: A0|A1|B0|B1, 4096 u16 each
  const int dcap = *dptr;
  const int tid = threadIdx.x;
  const int lane = tid & 63, wave = tid >> 6;
  const int wm = wave >> 1, wn = wave & 1;    // 2x2 waves -> 64x64 per wave
  const int lp = lane & 15, lg = lane >> 4;

  const int bid = blockIdx.x;
  const int xcd = bid & 7;
  const int idx = bid >> 3;                 // 0..511 within XCD
  const int mt  = idx & 7;                  // m fastest -> B-panel L2 reuse
  const int nt  = (xcd << 6) | (idx >> 3);  // n-tile 0..511
  const int m0  = mt * 128;
  const int n0g = nt * 128;
  const int b = n0g >> 13, t0 = n0g & (T_ - 1);
  const size_t xtb = (size_t)b * (T_ + DPAD) * C_;

  // stage mapping: slot = q*256+tid; row = q*64 + (tid>>2); blk = tid&3 (linear)
  const int srow = tid >> 2;
  const int kblk = tid & 3;
  const u16* const gA  = W + (size_t)(m0 + srow) * 1024 + kblk * 8;
  const u16* const gB1 = Xt + xtb + (size_t)(DPAD + t0 + srow) * C_ + kblk * 8;
  const u16* const gB2 = gB1 - (size_t)dcap * C_ - 512;

  u16* const A0  = smem;
  u16* const A1  = smem + 4096;
  u16* const B0  = smem + 8192;
  u16* const B1s = smem + 12288;

  f32x4 acc[4][4];
#pragma unroll
  for (int i = 0; i < 4; ++i)
#pragma unroll
    for (int j = 0; j < 4; ++j) acc[i][j] = (f32x4){0.f, 0.f, 0.f, 0.f};

  // frag read offset: row*32 + lg*8 (contiguous 1KB per frag, no swizzle)
  const int roff = lp * 32 + lg * 8;

#define GL16(g_, l_) __builtin_amdgcn_global_load_lds(                         \
    (const __attribute__((address_space(1))) void*)(g_),                       \
    (__attribute__((address_space(3))) void*)(l_), 16, 0, 0)

#define STAGEA(u_, Ad_) do {                                                   \
    GL16(gA + (u_) * 32,                  (Ad_) + tid * 8);                    \
    GL16(gA + (u_) * 32 + 64 * 1024,      (Ad_) + 2048 + tid * 8);             \
  } while (0)

#define STAGEB(u_, Bd_, gB_) do {                                              \
    GL16((gB_) + (u_) * 32,               (Bd_) + tid * 8);                    \
    GL16((gB_) + (u_) * 32 + 64 * C_,     (Bd_) + 2048 + tid * 8);             \
  } while (0)

#define LGKM0 do { asm volatile("s_waitcnt lgkmcnt(0)" ::: "memory");          \
                   __builtin_amdgcn_sched_barrier(0); } while (0)
#define VMW0  do { asm volatile("s_waitcnt vmcnt(0)" ::: "memory");            \
                   __builtin_amdgcn_sched_barrier(0); } while (0)

#define TILE(Ab_, Bb_, STAGES) do {                                            \
    bf16x8 a_[4], bb_[4];                                                      \
    _Pragma("unroll") for (int j_ = 0; j_ < 4; ++j_)                           \
      bb_[j_] = *(const bf16x8*)((Bb_) + (wn * 64 + j_ * 16) * 32 + roff);     \
    _Pragma("unroll") for (int i_ = 0; i_ < 4; ++i_)                           \
      a_[i_]  = *(const bf16x8*)((Ab_) + (wm * 64 + i_ * 16) * 32 + roff);     \
    STAGES;                                                                    \
    LGKM0;                                                                     \
    __builtin_amdgcn_s_setprio(1);                                             \
    _Pragma("unroll") for (int i_ = 0; i_ < 4; ++i_)                           \
      _Pragma("unroll") for (int j_ = 0; j_ < 4; ++j_)                         \
        acc[i_][j_] = __builtin_amdgcn_mfma_f32_16x16x32_bf16(a_[i_], bb_[j_], acc[i_][j_], 0, 0, 0); \
    __builtin_amdgcn_s_setprio(0);                                             \
  } while (0)

  // prologue: stage tile 0 into buf 0, drain, publish
  STAGEA(0, A0); STAGEB(0, B0, gB1);
  VMW0;
  __builtin_amdgcn_s_barrier();

  for (int t = 0; t < 31; ++t) {
    const u16* gBs = (t < 15) ? gB1 : gB2;   // staging tile t+1: tap1 iff t+1 <= 15
    if (t & 1) {
      TILE(A1, B1s, { STAGEA(t + 1, A0);  STAGEB(t + 1, B0,  gBs); });
    } else {
      TILE(A0, B0,  { STAGEA(t + 1, A1);  STAGEB(t + 1, B1s, gBs); });
    }
    VMW0;
    __builtin_amdgcn_s_barrier();
  }
  // tile 31 (odd -> A1/B1s), no staging
  TILE(A1, B1s, );

  // epilogue: rows R..R+3 = (filter c0, gate c0, filter c0+1, gate c0+1)
  const int g4 = lane >> 4, p = lane & 15;
#pragma unroll
  for (int i = 0; i < 4; ++i) {
    const int R = m0 + wm * 64 + i * 16 + (g4 << 2);
    const float bi0 = b1[R], bi1 = b1[R + 1], bi2 = b1[R + 2], bi3 = b1[R + 3];
    const int c0 = R >> 1;
#pragma unroll
    for (int j = 0; j < 4; ++j) {
      const int ttc = t0 + wn * 64 + j * 16 + p;
      f32x4 v = acc[i][j];
      float z0 = tanh_(v[0] + bi0) * sigm_(v[1] + bi1);
      float z1 = tanh_(v[2] + bi2) * sigm_(v[3] + bi3);
      u32 pk = (u32)f2bf(z0) | ((u32)f2bf(z1) << 16);
      *(u32*)(Zt + (size_t)(b * T_ + ttc) * C_ + c0) = pk;
    }
  }
#undef GL16
#undef STAGEA
#undef STAGEB
#undef LGKM0
#undef VMW0
#undef TILE
}

// ---------------- GEMM2: [768x512] x z + residual/skip epilogue ----------------
// k-loop: proven drain structure. Epilogue: per-wave LDS transpose in disjoint
// region -> f32x4 coalesced x-loads / out-stores along t.
__global__ __launch_bounds__(256, 4) void gemm2_kernel(
    const u16* __restrict__ W2, const u16* __restrict__ Zt,
    const float* __restrict__ b2, const float* __restrict__ x,
    float* __restrict__ out)
{
  __shared__ __align__(16) u16 As[128 * 32];
  __shared__ __align__(16) u16 Bs[128 * 32];
  __shared__ __align__(16) float fstall[4 * 1088];   // 4 waves x 16x68 padded
  const int tid = threadIdx.x;
  const int lane = tid & 63, wave = tid >> 6;
  const int wm = wave >> 1, wn = wave & 1;

  const int bid = blockIdx.x;
  const int xcd = bid & 7;
  const int idx = bid >> 3;            // 0..383
  const int mt  = idx % 6;
  const int nt  = (xcd << 6) + idx / 6;
  const int m0 = mt * 128;
  const int n0g = nt * 128;
  const int b = n0g >> 13, t0 = n0g & (T_ - 1);
  const int srow = tid >> 2;
  const int skk  = (tid & 3) * 8;

  f32x4 acc[4][4];
#pragma unroll
  for (int i = 0; i < 4; ++i)
#pragma unroll
    for (int j = 0; j < 4; ++j) acc[i][j] = (f32x4){0.f, 0.f, 0.f, 0.f};

  const int aoff = (wm * 64 + (lane & 15)) * 32 + (lane >> 4) * 8;
  const int boff = (wn * 64 + (lane & 15)) * 32 + (lane >> 4) * 8;
  const size_t ztb = (size_t)b * T_ * C_;

  for (int kc = 0; kc < 16; ++kc) {
    const int k = kc * 32 + skk;        // 0..511
    const u16* gA = W2 + (size_t)(m0 + srow) * 512 + k;
    const u16* gB = Zt + ztb + (size_t)(t0 + srow) * C_ + k;
    gload_lds16(gA,            As + tid * 8);
    gload_lds16(gA + 64 * 512, As + 2048 + tid * 8);
    gload_lds16(gB,            Bs + tid * 8);
    gload_lds16(gB + 64 * C_,  Bs + 2048 + tid * 8);
    asm volatile("s_waitcnt vmcnt(0)" ::: "memory");
    __syncthreads();
    bf16x8 af[4], bfr[4];
#pragma unroll
    for (int i = 0; i < 4; ++i) af[i]  = *(const bf16x8*)(As + aoff + i * 512);
#pragma unroll
    for (int j = 0; j < 4; ++j) bfr[j] = *(const bf16x8*)(Bs + boff + j * 512);
#pragma unroll
    for (int i = 0; i < 4; ++i)
#pragma unroll
      for (int j = 0; j < 4; ++j)
        acc[i][j] = __builtin_amdgcn_mfma_f32_16x16x32_bf16(af[i], bfr[j], acc[i][j], 0, 0, 0);
    __syncthreads();
  }

  // ---- coalesced epilogue: per-wave private LDS transpose of 16x64 quadrants ----
  float* const fst = fstall + wave * 1088;         // 16 rows x 68 (padded)
  const int g = lane >> 4, p = lane & 15;
  const bool isres = (m0 < 512);

#pragma unroll
  for (int i = 0; i < 4; ++i) {
#pragma unroll
    for (int j = 0; j < 4; ++j)
#pragma unroll
      for (int r = 0; r < 4; ++r)
        fst[(g * 4 + r) * 68 + j * 16 + p] = acc[i][j][r];
#pragma unroll
    for (int q = 0; q < 4; ++q) {
      const int lrow = q * 4 + g;                  // 0..15
      const int row = m0 + wm * 64 + i * 16 + lrow;
      const int t = t0 + wn * 64 + p * 4;
      f32x4 v = *(const f32x4*)&fst[lrow * 68 + p * 4];
      const float bias = b2[row];
      f32x4 res;
      if (isres) {
        const size_t o = ((size_t)(b * 512 + row)) * T_ + t;
        f32x4 xv = *(const f32x4*)(x + o);
#pragma unroll
        for (int e = 0; e < 4; ++e)
          res[e] = (xv[e] + v[e] + bias) * 0.70710678118654752f;
        *(f32x4*)(out + o) = res;
      } else {
        const size_t o = (size_t)33554432 + ((size_t)(b * 256 + (row - 512))) * T_ + t;
#pragma unroll
        for (int e = 0; e < 4; ++e)
          res[e] = v[e] + bias;
        *(f32x4*)(out + o) = res;
      }
    }
  }
}

extern "C" void kernel_launch(void* const* d_in, const int* in_sizes, int n_in,
                              void* d_out, int out_size, void* d_ws, size_t ws_size,
                              hipStream_t stream) {
  const float* x  = (const float*)d_in[0];
  const float* fw = (const float*)d_in[1];
  const float* fb = (const float*)d_in[2];
  const float* gw = (const float*)d_in[3];
  const float* gb = (const float*)d_in[4];
  const float* rw = (const float*)d_in[5];
  const float* rb = (const float*)d_in[6];
  const float* sw = (const float*)d_in[7];
  const float* sb = (const float*)d_in[8];
  const int* dil  = (const int*)d_in[9];

  char* ws = (char*)d_ws;
  u16*   Wbig = (u16*)(ws + OFF_WBIG);
  u16*   W2   = (u16*)(ws + OFF_W2);
  float* b1   = (float*)(ws + OFF_B1);
  float* b2   = (float*)(ws + OFF_B2);
  u16*   Xt   = (u16*)(ws + OFF_XT);
  u16*   Zt   = (u16*)(ws + OFF_ZT);
  float* out  = (float*)d_out;

  hipLaunchKernelGGL(pack_kernel, dim3(5767), dim3(256), 0, stream,
                     fw, fb, gw, gb, rw, rb, sw, sb, Wbig, W2, b1, b2, Xt);
  hipLaunchKernelGGL(transpose_kernel, dim3(8192), dim3(256), 0, stream, x, Xt);
  hipLaunchKernelGGL(gemm1_kernel, dim3(4096), dim3(256), 0, stream, Wbig, Xt, b1, Zt, dil);
  hipLaunchKernelGGL(gemm2_kernel, dim3(3072), dim3(256), 0, stream, W2, Zt, b2, x, out);
}

// Round 13
// 318.832 us; speedup vs baseline: 3.9916x; 3.9916x over previous
//
#include <hip/hip_runtime.h>
#include <hip/hip_bf16.h>

typedef __attribute__((ext_vector_type(4))) float f32x4;
typedef __attribute__((ext_vector_type(8))) short bf16x8;
typedef unsigned int   u32;
typedef unsigned short u16;

#define DPAD 8
#define B_   8
#define C_   512
#define T_   8192
#define S_   256

// workspace byte offsets
#define OFF_WBIG 0u          // u16[1024*1024]      = 2,097,152 B
#define OFF_W2   2097152u    // u16[768*512]        =   786,432 B
#define OFF_B1   2883584u    // float[1024]
#define OFF_B2   2887680u    // float[768]
#define OFF_XT   2891776u    // u16[8*(8192+8)*512] = 67,174,400 B
#define OFF_ZT   70066176u   // u16[8*8192*512]     = 67,108,864 B

__device__ __forceinline__ u16 f2bf(float f) {
  u32 u = __builtin_bit_cast(u32, f);
  u += 0x7FFFu + ((u >> 16) & 1u);
  return (u16)(u >> 16);
}
__device__ __forceinline__ float sigm_(float x) { return 1.0f / (1.0f + __expf(-x)); }
__device__ __forceinline__ float tanh_(float x) { return 2.0f / (1.0f + __expf(-2.0f * x)) - 1.0f; }

__device__ __forceinline__ void gload_lds16(const void* g, void* l) {
  __builtin_amdgcn_global_load_lds(
      (const __attribute__((address_space(1))) void*)g,
      (__attribute__((address_space(3))) void*)l, 16, 0, 0);
}

// ---------------- pack weights / biases, zero Xt pad rows ----------------
__global__ void pack_kernel(const float* __restrict__ fw, const float* __restrict__ fb,
                            const float* __restrict__ gw, const float* __restrict__ gb,
                            const float* __restrict__ rw, const float* __restrict__ rb,
                            const float* __restrict__ sw, const float* __restrict__ sb,
                            u16* __restrict__ Wbig, u16* __restrict__ W2,
                            float* __restrict__ b1, float* __restrict__ b2,
                            u16* __restrict__ Xt)
{
  int idx = blockIdx.x * 256 + threadIdx.x;
  if (idx < 1048576) {                    // Wbig[row][k], row 2i=filter i, 2i+1=gate i
    int row = idx >> 10, k = idx & 1023;  // k<512: tap1 (x[t]); k>=512: tap0 (x[t-d])
    int i = row >> 1;
    const float* src = (row & 1) ? gw : fw;
    float v = src[((i << 9) + (k & 511)) * 2 + ((k < 512) ? 1 : 0)];
    Wbig[idx] = f2bf(v);
    return;
  }
  idx -= 1048576;
  if (idx < 393216) {                     // W2[r][k]: r<512 res, else skip
    int r = idx >> 9, k = idx & 511;
    float v = (r < 512) ? rw[(r << 9) + k] : sw[((r - 512) << 9) + k];
    W2[idx] = f2bf(v);
    return;
  }
  idx -= 393216;
  if (idx < 1024) { b1[idx] = (idx & 1) ? gb[idx >> 1] : fb[idx >> 1]; return; }
  idx -= 1024;
  if (idx < 768) { b2[idx] = (idx < 512) ? rb[idx] : sb[idx - 512]; return; }
  idx -= 768;
  if (idx < B_ * DPAD * C_) {             // zero causal pad rows of Xt
    int b = idx >> 12;                    // DPAD*C_ = 4096
    int rest = idx & 4095;
    Xt[(size_t)b * (T_ + DPAD) * C_ + rest] = 0;
  }
}

// ---------------- x [B][C][T] f32 -> Xt [B][DPAD+T][C] bf16 ----------------
__global__ __launch_bounds__(256) void transpose_kernel(const float* __restrict__ x,
                                                        u16* __restrict__ Xt)
{
  __shared__ float tile[64][65];
  int bid = blockIdx.x;
  int ct = bid & 7, tt = (bid >> 3) & 127, b = bid >> 10;
  int w = threadIdx.x >> 6, ln = threadIdx.x & 63;
  const float* xp = x + ((size_t)(b * C_ + ct * 64)) * T_ + tt * 64;
#pragma unroll
  for (int r = 0; r < 16; ++r) {
    int cl = r * 4 + w;
    tile[cl][ln] = xp[(size_t)cl * T_ + ln];
  }
  __syncthreads();
  u16* op = Xt + ((size_t)b * (T_ + DPAD) + DPAD + tt * 64) * C_ + ct * 64;
#pragma unroll
  for (int r = 0; r < 16; ++r) {
    int tl = r * 4 + w;
    op[(size_t)tl * C_ + ln] = f2bf(tile[ln][tl]);
  }
}

// ---------------- GEMM1: 256x256, BK=32, 8 waves, 3-buffer ring, true-T4 -----------
// Per tile t: {12 ds_read (buf t%3); stage tile t+2 -> buf (t+2)%3 (4 gloads);
//  lgkm(4) -> 16 MFMA; lgkm(0) -> 16 MFMA; vmcnt(4); s_barrier}.
// vmcnt(4) leaves t+2's 4 loads in flight => t+1 published; NEVER drains to 0
// in the main loop (the m218 counted-vmcnt lever; 2-buffer schemes can't do this).
// WAR: buf((t+2)%3) readers (tile t-1) drained lgkm(0) before the prior barrier.
// Swizzle both-sides (rule 21): 16B-block ^= (row&3) pre-applied to global src
// (sxk) and ds_read addr (aswz) -> balanced 8-cy b128 reads.
__global__ __launch_bounds__(512, 2) void gemm1_kernel(
    const u16* __restrict__ W, const u16* __restrict__ Xt,
    const float* __restrict__ b1, u16* __restrict__ Zt,
    const int* __restrict__ dptr)
{
  __shared__ __align__(16) u16 smem[49152];   // 96 KB: 3 x (A 8192 u16 | B 8192 u16)
  const int dcap = *dptr;
  const int tid = threadIdx.x;
  const int lane = tid & 63, wave = tid >> 6;
  const int wm = wave >> 2, wn = wave & 3;    // 2 x 4 waves -> 128x64 per wave
  const int lp = lane & 15, lg = lane >> 4;

  const int bid = blockIdx.x;
  const int xcd = bid & 7;
  const int idx = bid >> 3;                 // 0..127 within XCD
  const int mt  = idx & 3;                  // m fastest -> B-panel L2 reuse
  const int nt  = (xcd << 5) | (idx >> 2);  // n-tile 0..255
  const int m0  = mt * 256;
  const int n0g = nt * 256;
  const int b = n0g >> 13, t0 = n0g & (T_ - 1);
  const size_t xtb = (size_t)b * (T_ + DPAD) * C_;

  // stage mapping: 512 threads cover one 256x32 operand in 2 gloads (h=0,1)
  // slot = h*512+tid; row = h*128 + (tid>>2); blk = tid&3; dest = h*4096 + tid*8
  const int srow = tid >> 2;                    // 0..127
  const int sxk  = (((tid & 3) ^ (srow & 3)) << 3);   // pre-swizzled k-elem offset
  const u16* gAh[2];  const u16* gB1h[2]; const u16* gB2h[2];
#pragma unroll
  for (int h = 0; h < 2; ++h) {
    gAh[h]  = W + (size_t)(m0 + h * 128 + srow) * 1024 + sxk;
    gB1h[h] = Xt + xtb + (size_t)(DPAD + t0 + h * 128 + srow) * C_ + sxk;
    gB2h[h] = gB1h[h] - (size_t)dcap * C_ - 512;
  }

  // ds_read lane offsets: row*32 + (lg^(row&3))*8 ; row&3 == lp&3 for all frags
  const int aswz = ((lg ^ (lp & 3)) << 3);
  const int ardo = (wm * 128 + lp) * 32 + aswz;           // + i*512 per frag
  const int brdo = 8192 + (wn * 64 + lp) * 32 + aswz;     // + j*512 per frag

  f32x4 acc[8][4];
#pragma unroll
  for (int i = 0; i < 8; ++i)
#pragma unroll
    for (int j = 0; j < 4; ++j) acc[i][j] = (f32x4){0.f, 0.f, 0.f, 0.f};

#define GL16(g_, l_) __builtin_amdgcn_global_load_lds(                         \
    (const __attribute__((address_space(1))) void*)(g_),                       \
    (__attribute__((address_space(3))) void*)(l_), 16, 0, 0)

#define STAGE_(tt_, bufs_) do {                                                \
    const u16* gb0_ = ((tt_) < 16) ? gB1h[0] : gB2h[0];                        \
    const u16* gb1_ = ((tt_) < 16) ? gB1h[1] : gB2h[1];                        \
    GL16(gAh[0] + (tt_) * 32, smem + (bufs_) * 16384 + tid * 8);               \
    GL16(gAh[1] + (tt_) * 32, smem + (bufs_) * 16384 + 4096 + tid * 8);        \
    GL16(gb0_   + (tt_) * 32, smem + (bufs_) * 16384 + 8192 + tid * 8);        \
    GL16(gb1_   + (tt_) * 32, smem + (bufs_) * 16384 + 12288 + tid * 8);       \
  } while (0)

#define LGKM(n_) do { asm volatile("s_waitcnt lgkmcnt(" #n_ ")" ::: "memory"); \
                      __builtin_amdgcn_sched_barrier(0); } while (0)
#define VMW(n_)  do { asm volatile("s_waitcnt vmcnt(" #n_ ")" ::: "memory");   \
                      __builtin_amdgcn_sched_barrier(0); } while (0)

// one K-tile: compute buf bufc_, optionally stage tile tt_ into bufs_, end-wait
#define TILEB(bufc_, DOSTAGE, ENDW, DOBAR) do {                                \
    const u16* base_ = smem + (bufc_) * 16384;                                 \
    bf16x8 bb_[4], a_[8];                                                      \
    _Pragma("unroll") for (int j_ = 0; j_ < 4; ++j_)                           \
      bb_[j_] = *(const bf16x8*)(base_ + brdo + j_ * 512);                     \
    _Pragma("unroll") for (int i_ = 0; i_ < 4; ++i_)                           \
      a_[i_] = *(const bf16x8*)(base_ + ardo + i_ * 512);                      \
    _Pragma("unroll") for (int i_ = 4; i_ < 8; ++i_)                           \
      a_[i_] = *(const bf16x8*)(base_ + ardo + i_ * 512);                      \
    DOSTAGE;                                                                   \
    LGKM(4);                                                                   \
    __builtin_amdgcn_s_setprio(1);                                             \
    _Pragma("unroll") for (int i_ = 0; i_ < 4; ++i_)                           \
      _Pragma("unroll") for (int j_ = 0; j_ < 4; ++j_)                         \
        acc[i_][j_] = __builtin_amdgcn_mfma_f32_16x16x32_bf16(a_[i_], bb_[j_], acc[i_][j_], 0, 0, 0); \
    __builtin_amdgcn_s_setprio(0);                                             \
    LGKM(0);                                                                   \
    __builtin_amdgcn_s_setprio(1);                                             \
    _Pragma("unroll") for (int i_ = 4; i_ < 8; ++i_)                           \
      _Pragma("unroll") for (int j_ = 0; j_ < 4; ++j_)                         \
        acc[i_][j_] = __builtin_amdgcn_mfma_f32_16x16x32_bf16(a_[i_], bb_[j_], acc[i_][j_], 0, 0, 0); \
    __builtin_amdgcn_s_setprio(0);                                             \
    ENDW;                                                                      \
    DOBAR;                                                                     \
  } while (0)

#define SBAR __builtin_amdgcn_s_barrier()

  // prologue: stage tiles 0,1 into bufs 0,1; wait until t0 landed (4 left = t1)
  STAGE_(0, 0);
  STAGE_(1, 1);
  VMW(4);
  SBAR;

  // tiles 0..29: compute t%3, stage t+2 -> (t+2)%3, end-wait vmcnt(4)
  for (int g = 0; g < 10; ++g) {
    const int t = g * 3;
    TILEB(0, STAGE_(t + 2, 2), VMW(4), SBAR);
    TILEB(1, STAGE_(t + 3, 0), VMW(4), SBAR);
    TILEB(2, STAGE_(t + 4, 1), VMW(4), SBAR);
  }
  // tile 30 (buf 0): no staging; drain tile 31's loads
  TILEB(0, , VMW(0), SBAR);
  // tile 31 (buf 1): no staging, no end-wait/barrier
  TILEB(1, , , );

  // epilogue: rows R..R+3 = (filter c0, gate c0, filter c0+1, gate c0+1)
  const int g4 = lane >> 4, p = lane & 15;
#pragma unroll
  for (int i = 0; i < 8; ++i) {
    const int R = m0 + wm * 128 + i * 16 + (g4 << 2);
    const float bi0 = b1[R], bi1 = b1[R + 1], bi2 = b1[R + 2], bi3 = b1[R + 3];
    const int c0 = R >> 1;
#pragma unroll
    for (int j = 0; j < 4; ++j) {
      const int ttc = t0 + wn * 64 + j * 16 + p;
      f32x4 v = acc[i][j];
      float z0 = tanh_(v[0] + bi0) * sigm_(v[1] + bi1);
      float z1 = tanh_(v[2] + bi2) * sigm_(v[3] + bi3);
      u32 pk = (u32)f2bf(z0) | ((u32)f2bf(z1) << 16);
      *(u32*)(Zt + (size_t)(b * T_ + ttc) * C_ + c0) = pk;
    }
  }
#undef GL16
#undef STAGE_
#undef LGKM
#undef VMW
#undef TILEB
#undef SBAR
}

// ---------------- GEMM2: [768x512] x z + residual/skip epilogue ----------------
// k-loop: proven drain structure. Epilogue: per-wave LDS transpose in disjoint
// region -> f32x4 coalesced x-loads / out-stores along t.
__global__ __launch_bounds__(256, 4) void gemm2_kernel(
    const u16* __restrict__ W2, const u16* __restrict__ Zt,
    const float* __restrict__ b2, const float* __restrict__ x,
    float* __restrict__ out)
{
  __shared__ __align__(16) u16 As[128 * 32];
  __shared__ __align__(16) u16 Bs[128 * 32];
  __shared__ __align__(16) float fstall[4 * 1088];   // 4 waves x 16x68 padded
  const int tid = threadIdx.x;
  const int lane = tid & 63, wave = tid >> 6;
  const int wm = wave >> 1, wn = wave & 1;

  const int bid = blockIdx.x;
  const int xcd = bid & 7;
  const int idx = bid >> 3;            // 0..383
  const int mt  = idx % 6;
  const int nt  = (xcd << 6) + idx / 6;
  const int m0 = mt * 128;
  const int n0g = nt * 128;
  const int b = n0g >> 13, t0 = n0g & (T_ - 1);
  const int srow = tid >> 2;
  const int skk  = (tid & 3) * 8;

  f32x4 acc[4][4];
#pragma unroll
  for (int i = 0; i < 4; ++i)
#pragma unroll
    for (int j = 0; j < 4; ++j) acc[i][j] = (f32x4){0.f, 0.f, 0.f, 0.f};

  const int aoff = (wm * 64 + (lane & 15)) * 32 + (lane >> 4) * 8;
  const int boff = (wn * 64 + (lane & 15)) * 32 + (lane >> 4) * 8;
  const size_t ztb = (size_t)b * T_ * C_;

  for (int kc = 0; kc < 16; ++kc) {
    const int k = kc * 32 + skk;        // 0..511
    const u16* gA = W2 + (size_t)(m0 + srow) * 512 + k;
    const u16* gB = Zt + ztb + (size_t)(t0 + srow) * C_ + k;
    gload_lds16(gA,            As + tid * 8);
    gload_lds16(gA + 64 * 512, As + 2048 + tid * 8);
    gload_lds16(gB,            Bs + tid * 8);
    gload_lds16(gB + 64 * C_,  Bs + 2048 + tid * 8);
    asm volatile("s_waitcnt vmcnt(0)" ::: "memory");
    __syncthreads();
    bf16x8 af[4], bfr[4];
#pragma unroll
    for (int i = 0; i < 4; ++i) af[i]  = *(const bf16x8*)(As + aoff + i * 512);
#pragma unroll
    for (int j = 0; j < 4; ++j) bfr[j] = *(const bf16x8*)(Bs + boff + j * 512);
#pragma unroll
    for (int i = 0; i < 4; ++i)
#pragma unroll
      for (int j = 0; j < 4; ++j)
        acc[i][j] = __builtin_amdgcn_mfma_f32_16x16x32_bf16(af[i], bfr[j], acc[i][j], 0, 0, 0);
    __syncthreads();
  }

  // ---- coalesced epilogue: per-wave private LDS transpose of 16x64 quadrants ----
  float* const fst = fstall + wave * 1088;         // 16 rows x 68 (padded)
  const int g = lane >> 4, p = lane & 15;
  const bool isres = (m0 < 512);

#pragma unroll
  for (int i = 0; i < 4; ++i) {
#pragma unroll
    for (int j = 0; j < 4; ++j)
#pragma unroll
      for (int r = 0; r < 4; ++r)
        fst[(g * 4 + r) * 68 + j * 16 + p] = acc[i][j][r];
#pragma unroll
    for (int q = 0; q < 4; ++q) {
      const int lrow = q * 4 + g;                  // 0..15
      const int row = m0 + wm * 64 + i * 16 + lrow;
      const int t = t0 + wn * 64 + p * 4;
      f32x4 v = *(const f32x4*)&fst[lrow * 68 + p * 4];
      const float bias = b2[row];
      f32x4 res;
      if (isres) {
        const size_t o = ((size_t)(b * 512 + row)) * T_ + t;
        f32x4 xv = *(const f32x4*)(x + o);
#pragma unroll
        for (int e = 0; e < 4; ++e)
          res[e] = (xv[e] + v[e] + bias) * 0.70710678118654752f;
        *(f32x4*)(out + o) = res;
      } else {
        const size_t o = (size_t)33554432 + ((size_t)(b * 256 + (row - 512))) * T_ + t;
#pragma unroll
        for (int e = 0; e < 4; ++e)
          res[e] = v[e] + bias;
        *(f32x4*)(out + o) = res;
      }
    }
  }
}

extern "C" void kernel_launch(void* const* d_in, const int* in_sizes, int n_in,
                              void* d_out, int out_size, void* d_ws, size_t ws_size,
                              hipStream_t stream) {
  const float* x  = (const float*)d_in[0];
  const float* fw = (const float*)d_in[1];
  const float* fb = (const float*)d_in[2];
  const float* gw = (const float*)d_in[3];
  const float* gb = (const float*)d_in[4];
  const float* rw = (const float*)d_in[5];
  const float* rb = (const float*)d_in[6];
  const float* sw = (const float*)d_in[7];
  const float* sb = (const float*)d_in[8];
  const int* dil  = (const int*)d_in[9];

  char* ws = (char*)d_ws;
  u16*   Wbig = (u16*)(ws + OFF_WBIG);
  u16*   W2   = (u16*)(ws + OFF_W2);
  float* b1   = (float*)(ws + OFF_B1);
  float* b2   = (float*)(ws + OFF_B2);
  u16*   Xt   = (u16*)(ws + OFF_XT);
  u16*   Zt   = (u16*)(ws + OFF_ZT);
  float* out  = (float*)d_out;

  hipLaunchKernelGGL(pack_kernel, dim3(5767), dim3(256), 0, stream,
                     fw, fb, gw, gb, rw, rb, sw, sb, Wbig, W2, b1, b2, Xt);
  hipLaunchKernelGGL(transpose_kernel, dim3(8192), dim3(256), 0, stream, x, Xt);
  hipLaunchKernelGGL(gemm1_kernel, dim3(1024), dim3(512), 0, stream, Wbig, Xt, b1, Zt, dil);
  hipLaunchKernelGGL(gemm2_kernel, dim3(3072), dim3(256), 0, stream, W2, Zt, b2, x, out);
}

// Round 14
// 314.601 us; speedup vs baseline: 4.0453x; 1.0134x over previous
//
#include <hip/hip_runtime.h>
#include <hip/hip_bf16.h>

typedef __attribute__((ext_vector_type(4))) float f32x4;
typedef __attribute__((ext_vector_type(8))) short bf16x8;
typedef unsigned int   u32;
typedef unsigned short u16;

#define DPAD 8
#define B_   8
#define C_   512
#define T_   8192
#define S_   256

// workspace byte offsets
#define OFF_WBIG 0u          // u16[1024*1024]      = 2,097,152 B
#define OFF_W2   2097152u    // u16[768*512]        =   786,432 B
#define OFF_B1   2883584u    // float[1024]
#define OFF_B2   2887680u    // float[768]
#define OFF_XT   2891776u    // u16[8*(8192+8)*512] = 67,174,400 B
#define OFF_ZT   70066176u   // u16[8*8192*512]     = 67,108,864 B

__device__ __forceinline__ u16 f2bf(float f) {
  u32 u = __builtin_bit_cast(u32, f);
  u += 0x7FFFu + ((u >> 16) & 1u);
  return (u16)(u >> 16);
}
__device__ __forceinline__ float sigm_(float x) { return 1.0f / (1.0f + __expf(-x)); }
__device__ __forceinline__ float tanh_(float x) { return 2.0f / (1.0f + __expf(-2.0f * x)) - 1.0f; }

__device__ __forceinline__ void gload_lds16(const void* g, void* l) {
  __builtin_amdgcn_global_load_lds(
      (const __attribute__((address_space(1))) void*)g,
      (__attribute__((address_space(3))) void*)l, 16, 0, 0);
}

// ---------------- pack weights / biases, zero Xt pad rows ----------------
__global__ void pack_kernel(const float* __restrict__ fw, const float* __restrict__ fb,
                            const float* __restrict__ gw, const float* __restrict__ gb,
                            const float* __restrict__ rw, const float* __restrict__ rb,
                            const float* __restrict__ sw, const float* __restrict__ sb,
                            u16* __restrict__ Wbig, u16* __restrict__ W2,
                            float* __restrict__ b1, float* __restrict__ b2,
                            u16* __restrict__ Xt)
{
  int idx = blockIdx.x * 256 + threadIdx.x;
  if (idx < 1048576) {                    // Wbig[row][k], row 2i=filter i, 2i+1=gate i
    int row = idx >> 10, k = idx & 1023;  // k<512: tap1 (x[t]); k>=512: tap0 (x[t-d])
    int i = row >> 1;
    const float* src = (row & 1) ? gw : fw;
    float v = src[((i << 9) + (k & 511)) * 2 + ((k < 512) ? 1 : 0)];
    Wbig[idx] = f2bf(v);
    return;
  }
  idx -= 1048576;
  if (idx < 393216) {                     // W2[r][k]: r<512 res, else skip
    int r = idx >> 9, k = idx & 511;
    float v = (r < 512) ? rw[(r << 9) + k] : sw[((r - 512) << 9) + k];
    W2[idx] = f2bf(v);
    return;
  }
  idx -= 393216;
  if (idx < 1024) { b1[idx] = (idx & 1) ? gb[idx >> 1] : fb[idx >> 1]; return; }
  idx -= 1024;
  if (idx < 768) { b2[idx] = (idx < 512) ? rb[idx] : sb[idx - 512]; return; }
  idx -= 768;
  if (idx < B_ * DPAD * C_) {             // zero causal pad rows of Xt
    int b = idx >> 12;                    // DPAD*C_ = 4096
    int rest = idx & 4095;
    Xt[(size_t)b * (T_ + DPAD) * C_ + rest] = 0;
  }
}

// ---------------- x [B][C][T] f32 -> Xt [B][DPAD+T][C] bf16 ----------------
__global__ __launch_bounds__(256) void transpose_kernel(const float* __restrict__ x,
                                                        u16* __restrict__ Xt)
{
  __shared__ float tile[64][65];
  int bid = blockIdx.x;
  int ct = bid & 7, tt = (bid >> 3) & 127, b = bid >> 10;
  int w = threadIdx.x >> 6, ln = threadIdx.x & 63;
  const float* xp = x + ((size_t)(b * C_ + ct * 64)) * T_ + tt * 64;
#pragma unroll
  for (int r = 0; r < 16; ++r) {
    int cl = r * 4 + w;
    tile[cl][ln] = xp[(size_t)cl * T_ + ln];
  }
  __syncthreads();
  u16* op = Xt + ((size_t)b * (T_ + DPAD) + DPAD + tt * 64) * C_ + ct * 64;
#pragma unroll
  for (int r = 0; r < 16; ++r) {
    int tl = r * 4 + w;
    op[(size_t)tl * C_ + ln] = f2bf(tile[ln][tl]);
  }
}

// ---------------- GEMM1: 256x256, BK=64, 8 waves, 1 barrier/K-tile -----------------
// k-loop: round-10 proven skeleton (passed twice, best measured). NEW: coalesced
// epilogue via per-wave LDS transpose (64t x 72c bf16) -> 32 contiguous 2x128B
// wave-stores instead of 64 scattered 64-line stores (16x fewer L2 transactions).
__global__ __launch_bounds__(512, 2) void gemm1_kernel(
    const u16* __restrict__ W, const u16* __restrict__ Xt,
    const float* __restrict__ b1, u16* __restrict__ Zt,
    const int* __restrict__ dptr)
{
  __shared__ __align__(16) u16 smem[65536];   // 128 KB: A0 A1 B0 B1 (32 KB each)
  const int dcap = *dptr;
  const int tid = threadIdx.x;
  const int lane = tid & 63, wave = tid >> 6;
  const int wm = wave >> 2, wn = wave & 3;    // 2 x 4 waves -> 128x64 per wave
  const int lp = lane & 15, lg = lane >> 4, lx = lane & 7;

  const int bid = blockIdx.x;
  const int xcd = bid & 7;
  const int idx = bid >> 3;                 // 0..127 within XCD
  const int mt  = idx & 3;                  // m fastest -> B-panel L2 reuse
  const int nt  = (xcd << 5) | (idx >> 2);  // n-tile 0..255
  const int m0  = mt * 256;
  const int n0g = nt * 256;
  const int b = n0g >> 13, t0 = n0g & (T_ - 1);
  const size_t xtb = (size_t)b * (T_ + DPAD) * C_;

  const int srl = tid >> 3;                 // stage row-in-quarter 0..63
  const int skb = tid & 7;                  // stage 16B-block 0..7
  const int sxk = (skb ^ (srl & 7)) << 3;   // swizzled k-elem offset 0..56

  f32x4 acc[8][4];
#pragma unroll
  for (int i = 0; i < 8; ++i)
#pragma unroll
    for (int j = 0; j < 4; ++j) acc[i][j] = (f32x4){0.f, 0.f, 0.f, 0.f};

#define SQA(kt_, dd, q_) do {                                                  \
    const int row_ = (q_) * 64 + srl;                                          \
    gload_lds16(W + (size_t)(m0 + row_) * 1024 + (kt_) * 64 + sxk,             \
                smem + (dd) * 16384 + (q_) * 4096 + tid * 8);                  \
  } while (0)

#define SQB(kt_, dd, q_) do {                                                  \
    const int row_ = (q_) * 64 + srl;                                          \
    const int kg_  = (kt_) * 64 + sxk;                                         \
    const int rsh_ = (kg_ >= 512) ? dcap : 0;                                  \
    gload_lds16(Xt + xtb + (size_t)(DPAD + t0 + row_ - rsh_) * C_ + (kg_ & 511), \
                smem + 32768 + (dd) * 16384 + (q_) * 4096 + tid * 8);          \
  } while (0)

#define LDA_(Ab_, f_, kk_) \
  (*(const bf16x8*)((Ab_) + (size_t)(wm * 128 + (f_) * 16 + lp) * 64 + ((((kk_) * 4 + lg) ^ lx) << 3)))
#define LDB_(Bb_, j_, kk_) \
  (*(const bf16x8*)((Bb_) + (size_t)(wn * 64 + (j_) * 16 + lp) * 64 + ((((kk_) * 4 + lg) ^ lx) << 3)))

#define READA(a_, p_, Ab_) do {                                                \
    a_[0] = LDA_(Ab_, 2 * (p_), 0);  a_[1] = LDA_(Ab_, 2 * (p_), 1);           \
    a_[2] = LDA_(Ab_, 2 * (p_) + 1, 0); a_[3] = LDA_(Ab_, 2 * (p_) + 1, 1);    \
  } while (0)

#define MFMAPH(a_, p_) do {                                                    \
    __builtin_amdgcn_s_setprio(1);                                             \
    _Pragma("unroll") for (int kk_ = 0; kk_ < 2; ++kk_) {                      \
      _Pragma("unroll") for (int j_ = 0; j_ < 4; ++j_)                         \
        acc[2*(p_)][j_]   = __builtin_amdgcn_mfma_f32_16x16x32_bf16(a_[kk_],     bfr[j_][kk_], acc[2*(p_)][j_],   0, 0, 0); \
      _Pragma("unroll") for (int j_ = 0; j_ < 4; ++j_)                         \
        acc[2*(p_)+1][j_] = __builtin_amdgcn_mfma_f32_16x16x32_bf16(a_[2 + kk_], bfr[j_][kk_], acc[2*(p_)+1][j_], 0, 0, 0); \
    }                                                                          \
    __builtin_amdgcn_s_setprio(0);                                             \
  } while (0)

#define LGKM(n_) do { asm volatile("s_waitcnt lgkmcnt(" #n_ ")" ::: "memory"); \
                      __builtin_amdgcn_sched_barrier(0); } while (0)
#define VMW(n_)  do { asm volatile("s_waitcnt vmcnt(" #n_ ")" ::: "memory");   \
                      __builtin_amdgcn_sched_barrier(0); } while (0)

  bf16x8 bfr[4][2];
  bf16x8 aW[4], aX[4];

  // prologue: stage tile 0 into buf 0, full drain, publish
  SQB(0, 0, 0); SQB(0, 0, 1); SQB(0, 0, 2); SQB(0, 0, 3);
  SQA(0, 0, 0); SQA(0, 0, 1); SQA(0, 0, 2); SQA(0, 0, 3);
  VMW(0);
  __builtin_amdgcn_s_barrier();

  for (int t = 0; t < 15; ++t) {
    const int dd = t & 1, de = dd ^ 1;
    const u16* Ab = smem + dd * 16384;
    const u16* Bb = smem + 32768 + dd * 16384;
#pragma unroll
    for (int j = 0; j < 4; ++j) { bfr[j][0] = LDB_(Bb, j, 0); bfr[j][1] = LDB_(Bb, j, 1); }
    READA(aW, 0, Ab);
    READA(aX, 1, Ab);
    LGKM(4);                 // B + aW ready; aX in flight
    MFMAPH(aW, 0);
    SQB(t + 1, de, 0); SQB(t + 1, de, 1); SQB(t + 1, de, 2); SQB(t + 1, de, 3);
    READA(aW, 2, Ab);
    LGKM(4);                 // aX ready
    MFMAPH(aX, 1);
    SQA(t + 1, de, 0); SQA(t + 1, de, 1); SQA(t + 1, de, 2); SQA(t + 1, de, 3);
    READA(aX, 3, Ab);
    LGKM(4);                 // aW' ready
    MFMAPH(aW, 2);
    LGKM(0);                 // aX' ready
    MFMAPH(aX, 3);
    VMW(0);                  // all 8 stages of t+1 landed
    __builtin_amdgcn_s_barrier();
  }
  {  // tile 15 (buf 1), no staging
    const u16* Ab = smem + 16384;
    const u16* Bb = smem + 49152;
#pragma unroll
    for (int j = 0; j < 4; ++j) { bfr[j][0] = LDB_(Bb, j, 0); bfr[j][1] = LDB_(Bb, j, 1); }
    READA(aW, 0, Ab);
    READA(aX, 1, Ab);
    LGKM(4);
    MFMAPH(aW, 0);
    READA(aW, 2, Ab);
    LGKM(4);
    MFMAPH(aX, 1);
    READA(aX, 3, Ab);
    LGKM(4);
    MFMAPH(aW, 2);
    LGKM(0);
    MFMAPH(aX, 3);
  }

  // ---- coalesced epilogue: per-wave 64t x 72c bf16 LDS transpose ----
  __syncthreads();                          // k-loop LDS dead; repurpose smem
  u16* const wt = smem + wave * 4608;       // 64 * 72 u16 per wave (9216 B)
  const int g4 = lane >> 4, p = lane & 15;
#pragma unroll
  for (int i = 0; i < 8; ++i) {
    const int R = m0 + wm * 128 + i * 16 + (g4 << 2);
    const float bi0 = b1[R], bi1 = b1[R + 1], bi2 = b1[R + 2], bi3 = b1[R + 3];
    const int cl = i * 8 + g4 * 2;          // wave-local channel (even, 0..62)
#pragma unroll
    for (int j = 0; j < 4; ++j) {
      f32x4 v = acc[i][j];
      float z0 = tanh_(v[0] + bi0) * sigm_(v[1] + bi1);
      float z1 = tanh_(v[2] + bi2) * sigm_(v[3] + bi3);
      u32 pk = (u32)f2bf(z0) | ((u32)f2bf(z1) << 16);
      *(u32*)(wt + (j * 16 + p) * 72 + cl) = pk;
    }
  }
  // wave-private region: same-wave DS ops in order, no barrier needed
  const int cg = (m0 >> 1) + wm * 64 + (lane & 31) * 2;   // global channel (even)
  const int l5 = lane >> 5;
#pragma unroll
  for (int s = 0; s < 32; ++s) {
    const int tl = s * 2 + l5;              // local t 0..63
    u32 v = *(const u32*)(wt + tl * 72 + (lane & 31) * 2);
    *(u32*)(Zt + (size_t)(b * T_ + t0 + wn * 64 + tl) * C_ + cg) = v;
  }
#undef SQA
#undef SQB
#undef LDA_
#undef LDB_
#undef READA
#undef MFMAPH
#undef LGKM
#undef VMW
}

// ---------------- GEMM2: [768x512] x z + residual/skip epilogue ----------------
// k-loop upgraded to the round-10 1-barrier overlap skeleton (2 buffers):
// {read frags(dd); stage t+1 -> de; lgkm(0); MFMA; vmcnt(0); s_barrier}.
// Epilogue unchanged (coalesced LDS transpose); fstall overlays k-loop LDS.
__global__ __launch_bounds__(256, 4) void gemm2_kernel(
    const u16* __restrict__ W2, const u16* __restrict__ Zt,
    const float* __restrict__ b2, const float* __restrict__ x,
    float* __restrict__ out)
{
  __shared__ __align__(16) u16 smem2[16384];   // 32 KB: As0|As1|Bs0|Bs1 (4096 u16 each)
  const int tid = threadIdx.x;
  const int lane = tid & 63, wave = tid >> 6;
  const int wm = wave >> 1, wn = wave & 1;

  const int bid = blockIdx.x;
  const int xcd = bid & 7;
  const int idx = bid >> 3;            // 0..383
  const int mt  = idx % 6;
  const int nt  = (xcd << 6) + idx / 6;
  const int m0 = mt * 128;
  const int n0g = nt * 128;
  const int b = n0g >> 13, t0 = n0g & (T_ - 1);
  const int srow = tid >> 2;
  const int skk  = (tid & 3) * 8;

  f32x4 acc[4][4];
#pragma unroll
  for (int i = 0; i < 4; ++i)
#pragma unroll
    for (int j = 0; j < 4; ++j) acc[i][j] = (f32x4){0.f, 0.f, 0.f, 0.f};

  const int aoff = (wm * 64 + (lane & 15)) * 32 + (lane >> 4) * 8;
  const int boff = (wn * 64 + (lane & 15)) * 32 + (lane >> 4) * 8;
  const size_t ztb = (size_t)b * T_ * C_;

  u16* const As[2] = { smem2,        smem2 + 4096 };
  u16* const Bs[2] = { smem2 + 8192, smem2 + 12288 };

#define STAGE2(dd_, kc_) do {                                                  \
    const int k_ = (kc_) * 32 + skk;                                           \
    gload_lds16(W2 + (size_t)(m0 + srow) * 512 + k_,           As[dd_] + tid * 8); \
    gload_lds16(W2 + (size_t)(m0 + 64 + srow) * 512 + k_,      As[dd_] + 2048 + tid * 8); \
    gload_lds16(Zt + ztb + (size_t)(t0 + srow) * C_ + k_,      Bs[dd_] + tid * 8); \
    gload_lds16(Zt + ztb + (size_t)(t0 + 64 + srow) * C_ + k_, Bs[dd_] + 2048 + tid * 8); \
  } while (0)

#define LGKM0 do { asm volatile("s_waitcnt lgkmcnt(0)" ::: "memory");          \
                   __builtin_amdgcn_sched_barrier(0); } while (0)
#define VMW0  do { asm volatile("s_waitcnt vmcnt(0)" ::: "memory");            \
                   __builtin_amdgcn_sched_barrier(0); } while (0)

  // prologue
  STAGE2(0, 0);
  VMW0;
  __builtin_amdgcn_s_barrier();

  for (int kc = 0; kc < 15; ++kc) {
    const int dd = kc & 1, de = dd ^ 1;
    bf16x8 af[4], bfr[4];
#pragma unroll
    for (int i = 0; i < 4; ++i) af[i]  = *(const bf16x8*)(As[dd] + aoff + i * 512);
#pragma unroll
    for (int j = 0; j < 4; ++j) bfr[j] = *(const bf16x8*)(Bs[dd] + boff + j * 512);
    STAGE2(de, kc + 1);
    LGKM0;
    __builtin_amdgcn_s_setprio(1);
#pragma unroll
    for (int i = 0; i < 4; ++i)
#pragma unroll
      for (int j = 0; j < 4; ++j)
        acc[i][j] = __builtin_amdgcn_mfma_f32_16x16x32_bf16(af[i], bfr[j], acc[i][j], 0, 0, 0);
    __builtin_amdgcn_s_setprio(0);
    VMW0;
    __builtin_amdgcn_s_barrier();
  }
  {  // kc = 15 (buf 1), no staging
    bf16x8 af[4], bfr[4];
#pragma unroll
    for (int i = 0; i < 4; ++i) af[i]  = *(const bf16x8*)(As[1] + aoff + i * 512);
#pragma unroll
    for (int j = 0; j < 4; ++j) bfr[j] = *(const bf16x8*)(Bs[1] + boff + j * 512);
    LGKM0;
#pragma unroll
    for (int i = 0; i < 4; ++i)
#pragma unroll
      for (int j = 0; j < 4; ++j)
        acc[i][j] = __builtin_amdgcn_mfma_f32_16x16x32_bf16(af[i], bfr[j], acc[i][j], 0, 0, 0);
  }

  // ---- coalesced epilogue: per-wave private LDS transpose of 16x64 quadrants ----
  __syncthreads();                              // k-loop LDS dead; overlay fstall
  float* const fst = (float*)smem2 + wave * 1088;   // 16 rows x 68 (padded)
  const int g = lane >> 4, p = lane & 15;
  const bool isres = (m0 < 512);

#pragma unroll
  for (int i = 0; i < 4; ++i) {
#pragma unroll
    for (int j = 0; j < 4; ++j)
#pragma unroll
      for (int r = 0; r < 4; ++r)
        fst[(g * 4 + r) * 68 + j * 16 + p] = acc[i][j][r];
#pragma unroll
    for (int q = 0; q < 4; ++q) {
      const int lrow = q * 4 + g;                  // 0..15
      const int row = m0 + wm * 64 + i * 16 + lrow;
      const int t = t0 + wn * 64 + p * 4;
      f32x4 v = *(const f32x4*)&fst[lrow * 68 + p * 4];
      const float bias = b2[row];
      f32x4 res;
      if (isres) {
        const size_t o = ((size_t)(b * 512 + row)) * T_ + t;
        f32x4 xv = *(const f32x4*)(x + o);
#pragma unroll
        for (int e = 0; e < 4; ++e)
          res[e] = (xv[e] + v[e] + bias) * 0.70710678118654752f;
        *(f32x4*)(out + o) = res;
      } else {
        const size_t o = (size_t)33554432 + ((size_t)(b * 256 + (row - 512))) * T_ + t;
#pragma unroll
        for (int e = 0; e < 4; ++e)
          res[e] = v[e] + bias;
        *(f32x4*)(out + o) = res;
      }
    }
  }
#undef STAGE2
#undef LGKM0
#undef VMW0
}

extern "C" void kernel_launch(void* const* d_in, const int* in_sizes, int n_in,
                              void* d_out, int out_size, void* d_ws, size_t ws_size,
                              hipStream_t stream) {
  const float* x  = (const float*)d_in[0];
  const float* fw = (const float*)d_in[1];
  const float* fb = (const float*)d_in[2];
  const float* gw = (const float*)d_in[3];
  const float* gb = (const float*)d_in[4];
  const float* rw = (const float*)d_in[5];
  const float* rb = (const float*)d_in[6];
  const float* sw = (const float*)d_in[7];
  const float* sb = (const float*)d_in[8];
  const int* dil  = (const int*)d_in[9];

  char* ws = (char*)d_ws;
  u16*   Wbig = (u16*)(ws + OFF_WBIG);
  u16*   W2   = (u16*)(ws + OFF_W2);
  float* b1   = (float*)(ws + OFF_B1);
  float* b2   = (float*)(ws + OFF_B2);
  u16*   Xt   = (u16*)(ws + OFF_XT);
  u16*   Zt   = (u16*)(ws + OFF_ZT);
  float* out  = (float*)d_out;

  hipLaunchKernelGGL(pack_kernel, dim3(5767), dim3(256), 0, stream,
                     fw, fb, gw, gb, rw, rb, sw, sb, Wbig, W2, b1, b2, Xt);
  hipLaunchKernelGGL(transpose_kernel, dim3(8192), dim3(256), 0, stream, x, Xt);
  hipLaunchKernelGGL(gemm1_kernel, dim3(1024), dim3(512), 0, stream, Wbig, Xt, b1, Zt, dil);
  hipLaunchKernelGGL(gemm2_kernel, dim3(3072), dim3(256), 0, stream, W2, Zt, b2, x, out);
}

// Round 15
// 307.420 us; speedup vs baseline: 4.1398x; 1.0234x over previous
//
#include <hip/hip_runtime.h>
#include <hip/hip_bf16.h>

typedef __attribute__((ext_vector_type(4))) float f32x4;
typedef __attribute__((ext_vector_type(8))) short bf16x8;
typedef __attribute__((ext_vector_type(4))) unsigned short u16x4;
typedef unsigned int   u32;
typedef unsigned short u16;

#define DPAD 8
#define B_   8
#define C_   512
#define T_   8192
#define S_   256

// workspace byte offsets
#define OFF_WBIG 0u          // u16[1024*1024]      = 2,097,152 B
#define OFF_W2   2097152u    // u16[768*512]        =   786,432 B
#define OFF_B1   2883584u    // float[1024]
#define OFF_B2   2887680u    // float[768]
#define OFF_XT   2891776u    // u16[8*(8192+8)*512] = 67,174,400 B
#define OFF_ZT   70066176u   // u16[8*8192*512]     = 67,108,864 B

__device__ __forceinline__ u16 f2bf(float f) {
  u32 u = __builtin_bit_cast(u32, f);
  u += 0x7FFFu + ((u >> 16) & 1u);
  return (u16)(u >> 16);
}
__device__ __forceinline__ float sigm_(float x) { return 1.0f / (1.0f + __expf(-x)); }
__device__ __forceinline__ float tanh_(float x) { return 2.0f / (1.0f + __expf(-2.0f * x)) - 1.0f; }

__device__ __forceinline__ void gload_lds16(const void* g, void* l) {
  __builtin_amdgcn_global_load_lds(
      (const __attribute__((address_space(1))) void*)g,
      (__attribute__((address_space(3))) void*)l, 16, 0, 0);
}

// ---------------- pack weights / biases, zero Xt pad rows ----------------
__global__ void pack_kernel(const float* __restrict__ fw, const float* __restrict__ fb,
                            const float* __restrict__ gw, const float* __restrict__ gb,
                            const float* __restrict__ rw, const float* __restrict__ rb,
                            const float* __restrict__ sw, const float* __restrict__ sb,
                            u16* __restrict__ Wbig, u16* __restrict__ W2,
                            float* __restrict__ b1, float* __restrict__ b2,
                            u16* __restrict__ Xt)
{
  int idx = blockIdx.x * 256 + threadIdx.x;
  if (idx < 1048576) {                    // Wbig[row][k], row 2i=filter i, 2i+1=gate i
    int row = idx >> 10, k = idx & 1023;  // k<512: tap1 (x[t]); k>=512: tap0 (x[t-d])
    int i = row >> 1;
    const float* src = (row & 1) ? gw : fw;
    float v = src[((i << 9) + (k & 511)) * 2 + ((k < 512) ? 1 : 0)];
    Wbig[idx] = f2bf(v);
    return;
  }
  idx -= 1048576;
  if (idx < 393216) {                     // W2[r][k]: r<512 res, else skip
    int r = idx >> 9, k = idx & 511;
    float v = (r < 512) ? rw[(r << 9) + k] : sw[((r - 512) << 9) + k];
    W2[idx] = f2bf(v);
    return;
  }
  idx -= 393216;
  if (idx < 1024) { b1[idx] = (idx & 1) ? gb[idx >> 1] : fb[idx >> 1]; return; }
  idx -= 1024;
  if (idx < 768) { b2[idx] = (idx < 512) ? rb[idx] : sb[idx - 512]; return; }
  idx -= 768;
  if (idx < B_ * DPAD * C_) {             // zero causal pad rows of Xt
    int b = idx >> 12;                    // DPAD*C_ = 4096
    int rest = idx & 4095;
    Xt[(size_t)b * (T_ + DPAD) * C_ + rest] = 0;
  }
}

// ---------------- x [B][C][T] f32 -> Xt [B][DPAD+T][C] bf16 ----------------
// Phase 1 unchanged (proven). Phase 2 vectorized: ushort4 stores (8 B/lane,
// 4x128B segments per wave-instr instead of 2 B/lane scatter).
__global__ __launch_bounds__(256) void transpose_kernel(const float* __restrict__ x,
                                                        u16* __restrict__ Xt)
{
  __shared__ float tile[64][65];
  int bid = blockIdx.x;
  int ct = bid & 7, tt = (bid >> 3) & 127, b = bid >> 10;
  int w = threadIdx.x >> 6, ln = threadIdx.x & 63;
  const float* xp = x + ((size_t)(b * C_ + ct * 64)) * T_ + tt * 64;
#pragma unroll
  for (int r = 0; r < 16; ++r) {
    int cl = r * 4 + w;
    tile[cl][ln] = xp[(size_t)cl * T_ + ln];
  }
  __syncthreads();
  u16* op = Xt + ((size_t)b * (T_ + DPAD) + DPAD + tt * 64) * C_ + ct * 64;
  const int q = threadIdx.x & 15;          // channel quad: c = 4q..4q+3
  const int cr = threadIdx.x >> 4;         // 0..15
#pragma unroll
  for (int r = 0; r < 4; ++r) {
    const int tl = r * 16 + cr;            // local t 0..63
    // LDS reads tile[4q+e][tl]: bank = (4q+e+tl)%32 -> 2-way (free)
    u16x4 v;
#pragma unroll
    for (int e = 0; e < 4; ++e) v[e] = f2bf(tile[q * 4 + e][tl]);
    *(u16x4*)(op + (size_t)tl * C_ + q * 4) = v;
  }
}

// ---------------- GEMM1: 256x256, BK=64, 8 waves, 1 barrier/K-tile -----------------
// Round-10 k-loop skeleton (best measured, passed 3x) + coalesced Zt epilogue.
// Structure ceiling for this session: MfmaUtil ~32% invariant across 8 schedule
// variants (drain/counted/ring/fine-phase/occupancy 21-46%); stopping here.
__global__ __launch_bounds__(512, 2) void gemm1_kernel(
    const u16* __restrict__ W, const u16* __restrict__ Xt,
    const float* __restrict__ b1, u16* __restrict__ Zt,
    const int* __restrict__ dptr)
{
  __shared__ __align__(16) u16 smem[65536];   // 128 KB: A0 A1 B0 B1 (32 KB each)
  const int dcap = *dptr;
  const int tid = threadIdx.x;
  const int lane = tid & 63, wave = tid >> 6;
  const int wm = wave >> 2, wn = wave & 3;    // 2 x 4 waves -> 128x64 per wave
  const int lp = lane & 15, lg = lane >> 4, lx = lane & 7;

  const int bid = blockIdx.x;
  const int xcd = bid & 7;
  const int idx = bid >> 3;                 // 0..127 within XCD
  const int mt  = idx & 3;                  // m fastest -> B-panel L2 reuse
  const int nt  = (xcd << 5) | (idx >> 2);  // n-tile 0..255
  const int m0  = mt * 256;
  const int n0g = nt * 256;
  const int b = n0g >> 13, t0 = n0g & (T_ - 1);
  const size_t xtb = (size_t)b * (T_ + DPAD) * C_;

  const int srl = tid >> 3;                 // stage row-in-quarter 0..63
  const int skb = tid & 7;                  // stage 16B-block 0..7
  const int sxk = (skb ^ (srl & 7)) << 3;   // swizzled k-elem offset 0..56

  f32x4 acc[8][4];
#pragma unroll
  for (int i = 0; i < 8; ++i)
#pragma unroll
    for (int j = 0; j < 4; ++j) acc[i][j] = (f32x4){0.f, 0.f, 0.f, 0.f};

#define SQA(kt_, dd, q_) do {                                                  \
    const int row_ = (q_) * 64 + srl;                                          \
    gload_lds16(W + (size_t)(m0 + row_) * 1024 + (kt_) * 64 + sxk,             \
                smem + (dd) * 16384 + (q_) * 4096 + tid * 8);                  \
  } while (0)

#define SQB(kt_, dd, q_) do {                                                  \
    const int row_ = (q_) * 64 + srl;                                          \
    const int kg_  = (kt_) * 64 + sxk;                                         \
    const int rsh_ = (kg_ >= 512) ? dcap : 0;                                  \
    gload_lds16(Xt + xtb + (size_t)(DPAD + t0 + row_ - rsh_) * C_ + (kg_ & 511), \
                smem + 32768 + (dd) * 16384 + (q_) * 4096 + tid * 8);          \
  } while (0)

#define LDA_(Ab_, f_, kk_) \
  (*(const bf16x8*)((Ab_) + (size_t)(wm * 128 + (f_) * 16 + lp) * 64 + ((((kk_) * 4 + lg) ^ lx) << 3)))
#define LDB_(Bb_, j_, kk_) \
  (*(const bf16x8*)((Bb_) + (size_t)(wn * 64 + (j_) * 16 + lp) * 64 + ((((kk_) * 4 + lg) ^ lx) << 3)))

#define READA(a_, p_, Ab_) do {                                                \
    a_[0] = LDA_(Ab_, 2 * (p_), 0);  a_[1] = LDA_(Ab_, 2 * (p_), 1);           \
    a_[2] = LDA_(Ab_, 2 * (p_) + 1, 0); a_[3] = LDA_(Ab_, 2 * (p_) + 1, 1);    \
  } while (0)

#define MFMAPH(a_, p_) do {                                                    \
    __builtin_amdgcn_s_setprio(1);                                             \
    _Pragma("unroll") for (int kk_ = 0; kk_ < 2; ++kk_) {                      \
      _Pragma("unroll") for (int j_ = 0; j_ < 4; ++j_)                         \
        acc[2*(p_)][j_]   = __builtin_amdgcn_mfma_f32_16x16x32_bf16(a_[kk_],     bfr[j_][kk_], acc[2*(p_)][j_],   0, 0, 0); \
      _Pragma("unroll") for (int j_ = 0; j_ < 4; ++j_)                         \
        acc[2*(p_)+1][j_] = __builtin_amdgcn_mfma_f32_16x16x32_bf16(a_[2 + kk_], bfr[j_][kk_], acc[2*(p_)+1][j_], 0, 0, 0); \
    }                                                                          \
    __builtin_amdgcn_s_setprio(0);                                             \
  } while (0)

#define LGKM(n_) do { asm volatile("s_waitcnt lgkmcnt(" #n_ ")" ::: "memory"); \
                      __builtin_amdgcn_sched_barrier(0); } while (0)
#define VMW(n_)  do { asm volatile("s_waitcnt vmcnt(" #n_ ")" ::: "memory");   \
                      __builtin_amdgcn_sched_barrier(0); } while (0)

  bf16x8 bfr[4][2];
  bf16x8 aW[4], aX[4];

  // prologue: stage tile 0 into buf 0, full drain, publish
  SQB(0, 0, 0); SQB(0, 0, 1); SQB(0, 0, 2); SQB(0, 0, 3);
  SQA(0, 0, 0); SQA(0, 0, 1); SQA(0, 0, 2); SQA(0, 0, 3);
  VMW(0);
  __builtin_amdgcn_s_barrier();

  for (int t = 0; t < 15; ++t) {
    const int dd = t & 1, de = dd ^ 1;
    const u16* Ab = smem + dd * 16384;
    const u16* Bb = smem + 32768 + dd * 16384;
#pragma unroll
    for (int j = 0; j < 4; ++j) { bfr[j][0] = LDB_(Bb, j, 0); bfr[j][1] = LDB_(Bb, j, 1); }
    READA(aW, 0, Ab);
    READA(aX, 1, Ab);
    LGKM(4);                 // B + aW ready; aX in flight
    MFMAPH(aW, 0);
    SQB(t + 1, de, 0); SQB(t + 1, de, 1); SQB(t + 1, de, 2); SQB(t + 1, de, 3);
    READA(aW, 2, Ab);
    LGKM(4);                 // aX ready
    MFMAPH(aX, 1);
    SQA(t + 1, de, 0); SQA(t + 1, de, 1); SQA(t + 1, de, 2); SQA(t + 1, de, 3);
    READA(aX, 3, Ab);
    LGKM(4);                 // aW' ready
    MFMAPH(aW, 2);
    LGKM(0);                 // aX' ready
    MFMAPH(aX, 3);
    VMW(0);                  // all 8 stages of t+1 landed
    __builtin_amdgcn_s_barrier();
  }
  {  // tile 15 (buf 1), no staging
    const u16* Ab = smem + 16384;
    const u16* Bb = smem + 49152;
#pragma unroll
    for (int j = 0; j < 4; ++j) { bfr[j][0] = LDB_(Bb, j, 0); bfr[j][1] = LDB_(Bb, j, 1); }
    READA(aW, 0, Ab);
    READA(aX, 1, Ab);
    LGKM(4);
    MFMAPH(aW, 0);
    READA(aW, 2, Ab);
    LGKM(4);
    MFMAPH(aX, 1);
    READA(aX, 3, Ab);
    LGKM(4);
    MFMAPH(aW, 2);
    LGKM(0);
    MFMAPH(aX, 3);
  }

  // ---- coalesced epilogue: per-wave 64t x 72c bf16 LDS transpose ----
  __syncthreads();                          // k-loop LDS dead; repurpose smem
  u16* const wt = smem + wave * 4608;       // 64 * 72 u16 per wave (9216 B)
  const int g4 = lane >> 4, p = lane & 15;
#pragma unroll
  for (int i = 0; i < 8; ++i) {
    const int R = m0 + wm * 128 + i * 16 + (g4 << 2);
    const float bi0 = b1[R], bi1 = b1[R + 1], bi2 = b1[R + 2], bi3 = b1[R + 3];
    const int cl = i * 8 + g4 * 2;          // wave-local channel (even, 0..62)
#pragma unroll
    for (int j = 0; j < 4; ++j) {
      f32x4 v = acc[i][j];
      float z0 = tanh_(v[0] + bi0) * sigm_(v[1] + bi1);
      float z1 = tanh_(v[2] + bi2) * sigm_(v[3] + bi3);
      u32 pk = (u32)f2bf(z0) | ((u32)f2bf(z1) << 16);
      *(u32*)(wt + (j * 16 + p) * 72 + cl) = pk;
    }
  }
  // wave-private region: same-wave DS ops in order, no barrier needed
  const int cg = (m0 >> 1) + wm * 64 + (lane & 31) * 2;   // global channel (even)
  const int l5 = lane >> 5;
#pragma unroll
  for (int s = 0; s < 32; ++s) {
    const int tl = s * 2 + l5;              // local t 0..63
    u32 v = *(const u32*)(wt + tl * 72 + (lane & 31) * 2);
    *(u32*)(Zt + (size_t)(b * T_ + t0 + wn * 64 + tl) * C_ + cg) = v;
  }
#undef SQA
#undef SQB
#undef LDA_
#undef LDB_
#undef READA
#undef MFMAPH
#undef LGKM
#undef VMW
}

// ---------------- GEMM2: [768x512] x z + residual/skip epilogue ----------------
// Reverted verbatim to the round-11 version (proven across 8 passing rounds,
// part of the best 305.8 us total): drain k-loop + disjoint fstall epilogue.
__global__ __launch_bounds__(256, 4) void gemm2_kernel(
    const u16* __restrict__ W2, const u16* __restrict__ Zt,
    const float* __restrict__ b2, const float* __restrict__ x,
    float* __restrict__ out)
{
  __shared__ __align__(16) u16 As[128 * 32];
  __shared__ __align__(16) u16 Bs[128 * 32];
  __shared__ __align__(16) float fstall[4 * 1088];   // 4 waves x 16x68 padded
  const int tid = threadIdx.x;
  const int lane = tid & 63, wave = tid >> 6;
  const int wm = wave >> 1, wn = wave & 1;

  const int bid = blockIdx.x;
  const int xcd = bid & 7;
  const int idx = bid >> 3;            // 0..383
  const int mt  = idx % 6;
  const int nt  = (xcd << 6) + idx / 6;
  const int m0 = mt * 128;
  const int n0g = nt * 128;
  const int b = n0g >> 13, t0 = n0g & (T_ - 1);
  const int srow = tid >> 2;
  const int skk  = (tid & 3) * 8;

  f32x4 acc[4][4];
#pragma unroll
  for (int i = 0; i < 4; ++i)
#pragma unroll
    for (int j = 0; j < 4; ++j) acc[i][j] = (f32x4){0.f, 0.f, 0.f, 0.f};

  const int aoff = (wm * 64 + (lane & 15)) * 32 + (lane >> 4) * 8;
  const int boff = (wn * 64 + (lane & 15)) * 32 + (lane >> 4) * 8;
  const size_t ztb = (size_t)b * T_ * C_;

  for (int kc = 0; kc < 16; ++kc) {
    const int k = kc * 32 + skk;        // 0..511
    const u16* gA = W2 + (size_t)(m0 + srow) * 512 + k;
    const u16* gB = Zt + ztb + (size_t)(t0 + srow) * C_ + k;
    gload_lds16(gA,            As + tid * 8);
    gload_lds16(gA + 64 * 512, As + 2048 + tid * 8);
    gload_lds16(gB,            Bs + tid * 8);
    gload_lds16(gB + 64 * C_,  Bs + 2048 + tid * 8);
    asm volatile("s_waitcnt vmcnt(0)" ::: "memory");
    __syncthreads();
    bf16x8 af[4], bfr[4];
#pragma unroll
    for (int i = 0; i < 4; ++i) af[i]  = *(const bf16x8*)(As + aoff + i * 512);
#pragma unroll
    for (int j = 0; j < 4; ++j) bfr[j] = *(const bf16x8*)(Bs + boff + j * 512);
#pragma unroll
    for (int i = 0; i < 4; ++i)
#pragma unroll
      for (int j = 0; j < 4; ++j)
        acc[i][j] = __builtin_amdgcn_mfma_f32_16x16x32_bf16(af[i], bfr[j], acc[i][j], 0, 0, 0);
    __syncthreads();
  }

  // ---- coalesced epilogue: per-wave private LDS transpose of 16x64 quadrants ----
  float* const fst = fstall + wave * 1088;         // 16 rows x 68 (padded)
  const int g = lane >> 4, p = lane & 15;
  const bool isres = (m0 < 512);

#pragma unroll
  for (int i = 0; i < 4; ++i) {
#pragma unroll
    for (int j = 0; j < 4; ++j)
#pragma unroll
      for (int r = 0; r < 4; ++r)
        fst[(g * 4 + r) * 68 + j * 16 + p] = acc[i][j][r];
#pragma unroll
    for (int q = 0; q < 4; ++q) {
      const int lrow = q * 4 + g;                  // 0..15
      const int row = m0 + wm * 64 + i * 16 + lrow;
      const int t = t0 + wn * 64 + p * 4;
      f32x4 v = *(const f32x4*)&fst[lrow * 68 + p * 4];
      const float bias = b2[row];
      f32x4 res;
      if (isres) {
        const size_t o = ((size_t)(b * 512 + row)) * T_ + t;
        f32x4 xv = *(const f32x4*)(x + o);
#pragma unroll
        for (int e = 0; e < 4; ++e)
          res[e] = (xv[e] + v[e] + bias) * 0.70710678118654752f;
        *(f32x4*)(out + o) = res;
      } else {
        const size_t o = (size_t)33554432 + ((size_t)(b * 256 + (row - 512))) * T_ + t;
#pragma unroll
        for (int e = 0; e < 4; ++e)
          res[e] = v[e] + bias;
        *(f32x4*)(out + o) = res;
      }
    }
  }
}

extern "C" void kernel_launch(void* const* d_in, const int* in_sizes, int n_in,
                              void* d_out, int out_size, void* d_ws, size_t ws_size,
                              hipStream_t stream) {
  const float* x  = (const float*)d_in[0];
  const float* fw = (const float*)d_in[1];
  const float* fb = (const float*)d_in[2];
  const float* gw = (const float*)d_in[3];
  const float* gb = (const float*)d_in[4];
  const float* rw = (const float*)d_in[5];
  const float* rb = (const float*)d_in[6];
  const float* sw = (const float*)d_in[7];
  const float* sb = (const float*)d_in[8];
  const int* dil  = (const int*)d_in[9];

  char* ws = (char*)d_ws;
  u16*   Wbig = (u16*)(ws + OFF_WBIG);
  u16*   W2   = (u16*)(ws + OFF_W2);
  float* b1   = (float*)(ws + OFF_B1);
  float* b2   = (float*)(ws + OFF_B2);
  u16*   Xt   = (u16*)(ws + OFF_XT);
  u16*   Zt   = (u16*)(ws + OFF_ZT);
  float* out  = (float*)d_out;

  hipLaunchKernelGGL(pack_kernel, dim3(5767), dim3(256), 0, stream,
                     fw, fb, gw, gb, rw, rb, sw, sb, Wbig, W2, b1, b2, Xt);
  hipLaunchKernelGGL(transpose_kernel, dim3(8192), dim3(256), 0, stream, x, Xt);
  hipLaunchKernelGGL(gemm1_kernel, dim3(1024), dim3(512), 0, stream, Wbig, Xt, b1, Zt, dil);
  hipLaunchKernelGGL(gemm2_kernel, dim3(3072), dim3(256), 0, stream, W2, Zt, b2, x, out);
}